// Round 7
// baseline (377.740 us; speedup 1.0000x reference)
//
#include <hip/hip_runtime.h>

typedef unsigned short u16;
typedef __attribute__((ext_vector_type(8))) short short8;
typedef __attribute__((ext_vector_type(8))) unsigned short ushort8_t;
typedef __attribute__((ext_vector_type(4))) float f32x4;
typedef __attribute__((ext_vector_type(2))) float v2f;

#define BATCH   16
#define CCH     512
#define NBOX    36
#define SS      26
#define INDIM   25088   // 512*49
#define HIDN    512
#define M_ROWS  416     // BATCH*26 — boxes n>=26 never reach an output
#define KSPLIT  56
#define KITERS  7       // per split, BK=64 -> 56*7*64 = 25088
#define NKB     392

__device__ __forceinline__ u16 f2bf(float f) {
  unsigned u = __float_as_uint(f);
  u += 0x7FFF + ((u >> 16) & 1);   // RNE
  return (u16)(u >> 16);
}
__device__ __forceinline__ float bf2f(u16 h) {
  return __uint_as_float(((unsigned)h) << 16);
}
__device__ __forceinline__ v2f bf2x2(u16 a, u16 b) {
  v2f r;
  r.x = __uint_as_float(((unsigned)a) << 16);
  r.y = __uint_as_float(((unsigned)b) << 16);
  return r;
}

// ---------------- kernel 1: transpose (j<4096) | roi (4096..4927) | convert
// (4928..6975) in ONE launch. roi job for image b waits on sem[b]==256 (its
// 256 transpose producers), fence pattern identical to the r5-verified gbar:
// producer: syncthreads (drains stores) -> threadfence release -> relaxed add;
// consumer: relaxed poll -> threadfence acquire -> syncthreads.
// Deadlock-impossible: <=832 spinners vs ~2048 resident-block capacity, and
// producers are dispatched first. Job-ID order puts roi right behind its
// producers so the 2048 convert blocks overlap roi instead of preceding it.
__global__ __launch_bounds__(256) void k_prep_roi(const float* __restrict__ lf,
                                                  const float* __restrict__ roiW,
                                                  const float* __restrict__ pred,
                                                  u16* __restrict__ lf_t,
                                                  u16* __restrict__ Wb2,
                                                  u16* __restrict__ flat2,
                                                  unsigned* __restrict__ sem) {
  __shared__ union {
    u16 tr[32][66];       // transpose: 4224 B
    u16 cv[49 * 132];     // convert chunk: 12936 B
    struct {
      int   ylo[14], yhi[14], xlo[14], xhi[14];
      float wyl[14], wyh[14], wxl[14], wxh[14];
    } roi;                // 448 B
  } sm;
  int j = blockIdx.x;
  int t = threadIdx.x;

  if (j < 4096) {
    // ---- transpose job: (B,C,H,W) f32 -> (B,HW,C) bf16
    int ct = j & 7, y = (j >> 3) & 31, b = j >> 8;
    int cl = t >> 2;            // 0..63 channel within tile
    int xq = (t & 3) * 8;       // 8 consecutive x
    const float* src = lf + ((size_t)(b * CCH + ct * 64 + cl) * 1024) + y * 32 + xq;
    float4 v0 = *(const float4*)src;
    float4 v1 = *(const float4*)(src + 4);
    sm.tr[xq + 0][cl] = f2bf(v0.x); sm.tr[xq + 1][cl] = f2bf(v0.y);
    sm.tr[xq + 2][cl] = f2bf(v0.z); sm.tr[xq + 3][cl] = f2bf(v0.w);
    sm.tr[xq + 4][cl] = f2bf(v1.x); sm.tr[xq + 5][cl] = f2bf(v1.y);
    sm.tr[xq + 6][cl] = f2bf(v1.z); sm.tr[xq + 7][cl] = f2bf(v1.w);
    __syncthreads();
    int xl = t >> 3;            // 0..31
    int cq = (t & 7) * 8;       // 8 consecutive channels
    ushort8_t o;
#pragma unroll
    for (int i = 0; i < 8; ++i) o[i] = sm.tr[xl][cq + i];
    *(ushort8_t*)(lf_t + ((size_t)b * 1024 + y * 32 + xl) * CCH + ct * 64 + cq) = o;
    __syncthreads();            // all waves' lf_t stores drained (vmcnt in barrier)
    if (t == 0) {
      __threadfence();          // agent release: visible to other XCDs
      __hip_atomic_fetch_add(sem + b * 32, 1u,
                             __ATOMIC_RELAXED, __HIP_MEMORY_SCOPE_AGENT);
    }
  } else if (j < 4928) {
    // ---- ROI half-box job (r2-r5-verified 256-thread body)
    int jj = j - 4096;                   // 0..831; 4096%8==0 keeps jj&7
    int half = (jj >= 416) ? 1 : 0;
    int bj   = half ? jj - 416 : jj;
    int xcd  = bj & 7;
    int s    = bj >> 3;                  // 0..51
    int b    = xcd * 2 + (s >= 26 ? 1 : 0);
    int n    = (s >= 26) ? s - 26 : s;   // always < 26
    int blk  = b * 26 + n;               // output row in M=416 space

    if (t == 0) {
      while (__hip_atomic_load(sem + b * 32, __ATOMIC_RELAXED,
                               __HIP_MEMORY_SCOPE_AGENT) < 256u)
        __builtin_amdgcn_s_sleep(16);
      __threadfence();          // agent acquire: invalidate stale lf_t lines
    }
    __syncthreads();

    if (t < 28) {
      bool isY = t < 14;
      int jt = isY ? t : t - 14;
      const float* pp = pred + ((size_t)(b * SS + n)) * 4;
      float c0 = pp[0], c1 = pp[1], c2 = pp[2], c3 = pp[3];
      float lo1 = (isY ? c1 : c0) * 32.f;
      float hi1 = (isY ? c3 : c2) * 32.f;
      float sz = fmaxf(hi1 - lo1, 1.f);
      float bs = sz * (1.f / 7.f);
      float off = (float)(jt >> 1) + 0.25f + 0.5f * (float)(jt & 1);
      float pos = lo1 + off * bs;
      bool valid = (pos > -1.f) && (pos < 32.f);
      float tc = fminf(fmaxf(pos, 0.f), 31.f);
      int lo = (int)floorf(tc);
      int hi = min(lo + 1, 31);
      float fr = tc - (float)lo;
      float wl = valid ? (1.f - fr) : 0.f;
      float wh = valid ? fr : 0.f;
      if (isY) { sm.roi.ylo[jt] = lo; sm.roi.yhi[jt] = hi;
                 sm.roi.wyl[jt] = wl; sm.roi.wyh[jt] = wh; }
      else     { sm.roi.xlo[jt] = lo; sm.roi.xhi[jt] = hi;
                 sm.roi.wxl[jt] = wl; sm.roi.wxh[jt] = wh; }
    }
    __syncthreads();

    int cgi = t & 63;          // channel group: channels cgi*8 .. cgi*8+7
    int pg  = t >> 6;          // 0..3
    const u16* base = lf_t + (size_t)b * 1024 * CCH + cgi * 8;
    int pend = half ? 49 : 24;

    for (int p = (half ? 24 : 0) + pg; p < pend; p += 4) {
      int py = p / 7, px = p % 7;
      v2f a0 = {0.f, 0.f}, a1 = {0.f, 0.f}, a2 = {0.f, 0.f}, a3 = {0.f, 0.f};
#pragma unroll
      for (int sy = 0; sy < 2; ++sy) {
        int jy = 2 * py + sy;
        const u16* rlo = base + sm.roi.ylo[jy] * 32 * CCH;
        const u16* rhi = base + sm.roi.yhi[jy] * 32 * CCH;
        float wyl = sm.roi.wyl[jy], wyh = sm.roi.wyh[jy];
#pragma unroll
        for (int sx = 0; sx < 2; ++sx) {
          int jx = 2 * px + sx;
          int xl = sm.roi.xlo[jx] * CCH, xh = sm.roi.xhi[jx] * CCH;
          v2f wll = {wyl * sm.roi.wxl[jx], wyl * sm.roi.wxl[jx]};
          v2f wlh = {wyl * sm.roi.wxh[jx], wyl * sm.roi.wxh[jx]};
          v2f whl = {wyh * sm.roi.wxl[jx], wyh * sm.roi.wxl[jx]};
          v2f whh = {wyh * sm.roi.wxh[jx], wyh * sm.roi.wxh[jx]};
          ushort8_t vll = *(const ushort8_t*)(rlo + xl);
          ushort8_t vlh = *(const ushort8_t*)(rlo + xh);
          ushort8_t vhl = *(const ushort8_t*)(rhi + xl);
          ushort8_t vhh = *(const ushort8_t*)(rhi + xh);
          a0 += wll * bf2x2(vll[0], vll[1]) + wlh * bf2x2(vlh[0], vlh[1])
              + whl * bf2x2(vhl[0], vhl[1]) + whh * bf2x2(vhh[0], vhh[1]);
          a1 += wll * bf2x2(vll[2], vll[3]) + wlh * bf2x2(vlh[2], vlh[3])
              + whl * bf2x2(vhl[2], vhl[3]) + whh * bf2x2(vhh[2], vhh[3]);
          a2 += wll * bf2x2(vll[4], vll[5]) + wlh * bf2x2(vlh[4], vlh[5])
              + whl * bf2x2(vhl[4], vhl[5]) + whh * bf2x2(vhh[4], vhh[5]);
          a3 += wll * bf2x2(vll[6], vll[7]) + wlh * bf2x2(vlh[6], vlh[7])
              + whl * bf2x2(vhl[6], vhl[7]) + whh * bf2x2(vhh[6], vhh[7]);
        }
      }
      ushort8_t o;
      o[0] = f2bf(a0.x * 0.25f); o[1] = f2bf(a0.y * 0.25f);
      o[2] = f2bf(a1.x * 0.25f); o[3] = f2bf(a1.y * 0.25f);
      o[4] = f2bf(a2.x * 0.25f); o[5] = f2bf(a2.y * 0.25f);
      o[6] = f2bf(a3.x * 0.25f); o[7] = f2bf(a3.y * 0.25f);
      int kb  = p * 8 + (cgi >> 3);
      int col = (cgi & 7) * 8;
      *(ushort8_t*)(flat2 + ((size_t)kb * M_ROWS + blk) * 64 + col) = o;
    }
  } else {
    // ---- convert chunk job: roi_fc_W f32 (k = c*49+p) -> Wb2[kb][h][64]
    int j2 = j - 4928;
    int h  = j2 >> 2;
    int c0 = (j2 & 3) * 128;    // channel chunk base
    const float4* s4 = (const float4*)(roiW + (size_t)h * INDIM + (size_t)c0 * 49);
    for (int i = t; i < 1568; i += 256) {   // 128*49/4 float4
      float4 v = s4[i];
      int k = i * 4;                         // local flat = cc*49 + p
#pragma unroll
      for (int jj = 0; jj < 4; ++jj) {
        int kk = k + jj;
        int cc = kk / 49;                    // const divide -> magic mul
        int p  = kk - cc * 49;
        sm.cv[p * 132 + cc] = f2bf((&v.x)[jj]);
      }
    }
    __syncthreads();
    // 784 ushort8 outputs: q -> p = q>>4, cc0 = (q&15)*8
    for (int q = t; q < 784; q += 256) {
      int p = q >> 4;
      int cc0 = (q & 15) * 8;
      const u16* sp = &sm.cv[p * 132 + cc0];
      ushort8_t o;
#pragma unroll
      for (int i = 0; i < 8; ++i) o[i] = sp[i];
      int c   = c0 + cc0;
      int kb  = p * 8 + (c >> 6);
      int col = c & 63;
      *(ushort8_t*)(Wb2 + ((size_t)kb * HIDN + h) * 64 + col) = o;
    }
  }
}

// ---------------- kernel 2: GEMM, split-K, bf16 MFMA (baseline-verified) ---
__global__ __launch_bounds__(256) void k_gemm(const u16* __restrict__ flat2,
                                              const u16* __restrict__ Wb2,
                                              u16* __restrict__ partials) {
  __shared__ u16 As[128 * 64];   // 16 KB
  __shared__ u16 Bs[128 * 64];   // 16 KB

  int tid = threadIdx.x;
  int wave = tid >> 6, lane = tid & 63;
  int wm = wave >> 1, wn = wave & 1;
  int quad = lane >> 4, r = lane & 15;
  int xb = r & 7;                       // read-side XOR key

  // XCD-owner decode: 896 blocks = 8 XCDs x 7 z x 16 (4 M-tiles x 4 N-tiles)
  int bid = blockIdx.x;
  int xcd = bid & 7;
  int slot = bid >> 3;                  // 0..111
  int z = xcd * 7 + (slot >> 4);        // 0..55
  int xy = slot & 15;
  int tileN0 = (xy & 3) * 128;
  int tileM0 = (xy >> 2) * 128;
  int kb0 = z * KITERS;

  size_t aoff[4], boff[4];
  int    ldso[4];
#pragma unroll
  for (int t = 0; t < 4; ++t) {
    int chunk = (wave * 4 + t) * 64 + lane;
    int row = chunk >> 3;
    int lc = chunk & 7;
    ldso[t] = row * 64 + ((lc ^ (row & 7)) << 3);
    int grow = min(tileM0 + row, M_ROWS - 1);     // clamp M tail
    aoff[t] = ((size_t)kb0 * M_ROWS + grow) * 64 + lc * 8;
    boff[t] = ((size_t)kb0 * HIDN + tileN0 + row) * 64 + lc * 8;
  }

  f32x4 acc[4][4];
#pragma unroll
  for (int mi = 0; mi < 4; ++mi)
#pragma unroll
    for (int ni = 0; ni < 4; ++ni) acc[mi][ni] = (f32x4){0.f, 0.f, 0.f, 0.f};

  short8 ra[4], rb[4];
#pragma unroll
  for (int t = 0; t < 4; ++t) {
    ra[t] = *(const short8*)(flat2 + aoff[t]);
    rb[t] = *(const short8*)(Wb2 + boff[t]);
  }

  for (int kt = 0; kt < KITERS; ++kt) {
#pragma unroll
    for (int t = 0; t < 4; ++t) {
      *(short8*)&As[ldso[t]] = ra[t];
      *(short8*)&Bs[ldso[t]] = rb[t];
    }
    __syncthreads();

    if (kt + 1 < KITERS) {
      size_t ak = (size_t)(kt + 1) * (M_ROWS * 64);
      size_t bk = (size_t)(kt + 1) * (HIDN * 64);
#pragma unroll
      for (int t = 0; t < 4; ++t) {
        ra[t] = *(const short8*)(flat2 + aoff[t] + ak);
        rb[t] = *(const short8*)(Wb2 + boff[t] + bk);
      }
    }

#pragma unroll
    for (int kk = 0; kk < 64; kk += 32) {
      int k8 = kk >> 3;                 // 0 or 4
      int pc = ((k8 + quad) ^ xb) << 3; // physical column (u16 units)
      short8 af[4], bfr[4];
#pragma unroll
      for (int mi = 0; mi < 4; ++mi)
        af[mi] = *(const short8*)&As[(wm * 64 + mi * 16 + r) * 64 + pc];
#pragma unroll
      for (int ni = 0; ni < 4; ++ni)
        bfr[ni] = *(const short8*)&Bs[(wn * 64 + ni * 16 + r) * 64 + pc];
#pragma unroll
      for (int mi = 0; mi < 4; ++mi)
#pragma unroll
        for (int ni = 0; ni < 4; ++ni)
          acc[mi][ni] = __builtin_amdgcn_mfma_f32_16x16x32_bf16(
              af[mi], bfr[ni], acc[mi][ni], 0, 0, 0);
    }
    __syncthreads();
  }

  u16* part = partials + (size_t)z * (M_ROWS * HIDN);
#pragma unroll
  for (int mi = 0; mi < 4; ++mi)
#pragma unroll
    for (int ni = 0; ni < 4; ++ni) {
      int row0 = tileM0 + wm * 64 + mi * 16 + quad * 4;
      int col = tileN0 + wn * 64 + ni * 16 + r;
#pragma unroll
      for (int reg = 0; reg < 4; ++reg) {
        int row = row0 + reg;
        if (row < M_ROWS) part[(size_t)row * HIDN + col] = f2bf(acc[mi][ni][reg]);
      }
    }
}

// ---------------- kernel 3: reduce split-K + bias + relu -> feats ----------
// 2-way z-split per output (28-deep chains, 208 blocks) + shfl_xor combine.
__global__ __launch_bounds__(256) void k_reduce(const u16* __restrict__ partials,
                                                const float* __restrict__ bias,
                                                float* __restrict__ feats) {
  int gid = blockIdx.x * 256 + threadIdx.x;   // < 53248
  int zh  = gid & 1;                          // z-half
  int idx = gid >> 1;                         // 0..26623
  int row = idx >> 6;
  int c0  = (idx & 63) * 8;
  float s[8] = {0.f, 0.f, 0.f, 0.f, 0.f, 0.f, 0.f, 0.f};
  const u16* p = partials + (size_t)row * HIDN + c0
               + (size_t)(zh * 28) * (M_ROWS * HIDN);
  for (int z = 0; z < 28; ++z) {
    ushort8_t v = *(const ushort8_t*)(p + (size_t)z * (M_ROWS * HIDN));
#pragma unroll
    for (int j = 0; j < 8; ++j) s[j] += bf2f(v[j]);
  }
#pragma unroll
  for (int j = 0; j < 8; ++j) s[j] += __shfl_xor(s[j], 1);
  if (zh == 0) {
    float4 o0, o1;
    const float* bi = bias + c0;
    o0.x = fmaxf(s[0] + bi[0], 0.f); o0.y = fmaxf(s[1] + bi[1], 0.f);
    o0.z = fmaxf(s[2] + bi[2], 0.f); o0.w = fmaxf(s[3] + bi[3], 0.f);
    o1.x = fmaxf(s[4] + bi[4], 0.f); o1.y = fmaxf(s[5] + bi[5], 0.f);
    o1.z = fmaxf(s[6] + bi[6], 0.f); o1.w = fmaxf(s[7] + bi[7], 0.f);
    float* dst = feats + (size_t)row * HIDN + c0;
    *(float4*)dst = o0;
    *(float4*)(dst + 4) = o1;
  }
}

// ---------------- kernel 4: all heads, one wave per output dot -------------
__device__ __forceinline__ float wave_red(float s) {
#pragma unroll
  for (int off = 32; off > 0; off >>= 1) s += __shfl_down(s, off);
  return s;
}

__device__ __forceinline__ float dot512(const float* __restrict__ f,
                                        const float* __restrict__ w, int lane) {
  const float4* f4 = (const float4*)f;
  const float4* w4 = (const float4*)w;
  float4 x0 = f4[lane], y0 = w4[lane];
  float4 x1 = f4[lane + 64], y1 = w4[lane + 64];
  return x0.x * y0.x + x0.y * y0.y + x0.z * y0.z + x0.w * y0.w +
         x1.x * y1.x + x1.y * y1.y + x1.z * y1.z + x1.w * y1.w;
}

__global__ __launch_bounds__(256) void k_heads(const float* __restrict__ feats,
                                               const float* __restrict__ pred,
                                               const float* __restrict__ cW,
                                               const float* __restrict__ cb,
                                               const float* __restrict__ pW,
                                               const float* __restrict__ pb,
                                               const float* __restrict__ lW,
                                               const float* __restrict__ lb,
                                               const float* __restrict__ gW,
                                               const float* __restrict__ gb,
                                               const int* __restrict__ lidx,
                                               const int* __restrict__ gidx,
                                               float* __restrict__ out) {
  int wid = blockIdx.x * 4 + (threadIdx.x >> 6);   // 0..4639
  int lane = threadIdx.x & 63;
  float sum = 0.f;

  if (wid < 1664) {                 // refined (B,26,4)
    int b = wid / 104, rr = wid % 104, s = rr >> 2, o = rr & 3;
    sum = dot512(feats + (size_t)(b * 26 + s) * HIDN,
                 cW + (size_t)(s * 4 + o) * HIDN, lane);
    sum = wave_red(sum);
    if (lane == 0) {
      const float* p = pred + (size_t)(b * SS + s) * 4;
      float wdt = p[2] - p[0], hgt = p[3] - p[1];
      float whv = (o & 1) ? hgt : wdt;
      out[wid] = p[o] + (sum + cb[s * 4 + o]) * whv;
    }
  } else if (wid < 2080) {          // presence (B,26)
    int i = wid - 1664;
    int b = i / 26, s = i % 26;
    sum = dot512(feats + (size_t)(b * 26 + s) * HIDN,
                 pW + (size_t)s * HIDN, lane);
    sum = wave_red(sum);
    if (lane == 0) out[1664 + i] = sum + pb[s];
  } else if (wid < 3616) {          // loc (B,12,8)
    int i = wid - 2080;
    int b = i / 96, rr = i % 96, l = rr >> 3, o = rr & 7;
    sum = dot512(feats + (size_t)(b * 26 + lidx[l]) * HIDN,
                 lW + (size_t)(l * 8 + o) * HIDN, lane);
    sum = wave_red(sum);
    if (lane == 0) out[2080 + b * 160 + rr] = sum + lb[l * 8 + o];
  } else {                          // grp (B,4,16), K = 6*512
    int i = wid - 3616;
    int b = i / 64, rr = i % 64, g = rr >> 4, o = rr & 15;
    const float* w = gW + (size_t)(g * 16 + o) * 3072;
#pragma unroll
    for (int jj = 0; jj < 6; ++jj) {
      sum += dot512(feats + (size_t)(b * 26 + gidx[g * 6 + jj]) * HIDN,
                    w + jj * 512, lane);
    }
    sum = wave_red(sum);
    if (lane == 0) out[2080 + b * 160 + 96 + rr] = sum + gb[g * 16 + o];
  }
}

// ---------------------------------------------------------------------------
extern "C" void kernel_launch(void* const* d_in, const int* in_sizes, int n_in,
                              void* d_out, int out_size, void* d_ws, size_t ws_size,
                              hipStream_t stream) {
  const float* lf      = (const float*)d_in[0];
  const float* pred    = (const float*)d_in[1];
  const float* roiW    = (const float*)d_in[2];
  const float* roiB    = (const float*)d_in[3];
  const float* cW      = (const float*)d_in[4];
  const float* cb      = (const float*)d_in[5];
  const float* pW      = (const float*)d_in[6];
  const float* pb      = (const float*)d_in[7];
  const float* lW      = (const float*)d_in[8];
  const float* lb      = (const float*)d_in[9];
  const float* gW      = (const float*)d_in[10];
  const float* gb      = (const float*)d_in[11];
  const int*   lidx    = (const int*)d_in[12];
  const int*   gidx    = (const int*)d_in[13];
  float* out = (float*)d_out;

  char* ws = (char*)d_ws;
  // region 0: lf_t (16.8 MB) then reused by partials bf16 (23.9 MB = 56*416*512*2)
  u16*   lf_t     = (u16*)ws;
  u16*   partials = (u16*)ws;
  u16*   Wb2   = (u16*)(ws + 33030144);                 // 25,690,112 B
  u16*   flat2 = (u16*)(ws + 33030144 + 25690112);      // 20,873,216 B used
  unsigned* sem = (unsigned*)(ws + 33030144 + 25690112 + 20873216); // 2 KB
  float* feats = (float*)(ws + 33030144 + 25690112 + 28901376); // 851,968 B used

  hipMemsetAsync((void*)sem, 0, 2048, stream);
  k_prep_roi<<<6976, 256, 0, stream>>>(lf, roiW, pred, lf_t, Wb2, flat2, sem);
  // NOTE: partials aliases lf_t's region; k_prep_roi (last reader of lf_t) is
  // stream-ordered before k_gemm (first writer of partials).
  k_gemm<<<896, 256, 0, stream>>>(flat2, Wb2, partials);
  k_reduce<<<208, 256, 0, stream>>>(partials, roiB, feats);
  k_heads<<<1160, 256, 0, stream>>>(feats, pred, cW, cb, pW, pb, lW, lb, gW, gb,
                                    lidx, gidx, out);
}

// Round 8
// 204.500 us; speedup vs baseline: 1.8471x; 1.8471x over previous
//
#include <hip/hip_runtime.h>

typedef unsigned short u16;
typedef __attribute__((ext_vector_type(8))) short short8;
typedef __attribute__((ext_vector_type(8))) unsigned short ushort8_t;
typedef __attribute__((ext_vector_type(4))) float f32x4;
typedef __attribute__((ext_vector_type(2))) float v2f;

#define BATCH   16
#define CCH     512
#define NBOX    36
#define SS      26
#define INDIM   25088   // 512*49
#define HIDN    512
#define M_ROWS  416     // BATCH*26 — boxes n>=26 never reach an output
#define KSPLIT  56
#define KITERS  7       // per split, BK=64 -> 56*7*64 = 25088
#define NKB     392

__device__ __forceinline__ u16 f2bf(float f) {
  unsigned u = __float_as_uint(f);
  u += 0x7FFF + ((u >> 16) & 1);   // RNE
  return (u16)(u >> 16);
}
__device__ __forceinline__ float bf2f(u16 h) {
  return __uint_as_float(((unsigned)h) << 16);
}
__device__ __forceinline__ v2f bf2x2(u16 a, u16 b) {
  v2f r;
  r.x = __uint_as_float(((unsigned)a) << 16);
  r.y = __uint_as_float(((unsigned)b) << 16);
  return r;
}

// ---------------- kernel 1: transpose jobs 0..4095 | convert jobs 4096..6143,
// 4 jobs per block (1536 blocks) to cut dispatch overhead. Bodies are the
// r6-verified ones; trailing __syncthreads() guards LDS reuse between jobs
// (same loop pattern as the r2-r5 fused phase 1, verified correct).
__global__ __launch_bounds__(256) void k_prep(const float* __restrict__ lf,
                                              const float* __restrict__ roiW,
                                              u16* __restrict__ lf_t,
                                              u16* __restrict__ Wb2) {
  __shared__ union {
    u16 tr[32][66];       // transpose: 4224 B
    u16 cv[49 * 132];     // convert chunk: 12936 B
  } sm;
  int t = threadIdx.x;

#pragma unroll 1
  for (int jj = 0; jj < 4; ++jj) {
    int j = blockIdx.x * 4 + jj;       // 0..6143
    if (j < 4096) {
      // ---- transpose job: (B,C,H,W) f32 -> (B,HW,C) bf16
      int ct = j & 7, y = (j >> 3) & 31, b = j >> 8;
      int cl = t >> 2;            // 0..63 channel within tile
      int xq = (t & 3) * 8;       // 8 consecutive x
      const float* src = lf + ((size_t)(b * CCH + ct * 64 + cl) * 1024) + y * 32 + xq;
      float4 v0 = *(const float4*)src;
      float4 v1 = *(const float4*)(src + 4);
      sm.tr[xq + 0][cl] = f2bf(v0.x); sm.tr[xq + 1][cl] = f2bf(v0.y);
      sm.tr[xq + 2][cl] = f2bf(v0.z); sm.tr[xq + 3][cl] = f2bf(v0.w);
      sm.tr[xq + 4][cl] = f2bf(v1.x); sm.tr[xq + 5][cl] = f2bf(v1.y);
      sm.tr[xq + 6][cl] = f2bf(v1.z); sm.tr[xq + 7][cl] = f2bf(v1.w);
      __syncthreads();
      int xl = t >> 3;            // 0..31
      int cq = (t & 7) * 8;       // 8 consecutive channels
      ushort8_t o;
#pragma unroll
      for (int i = 0; i < 8; ++i) o[i] = sm.tr[xl][cq + i];
      *(ushort8_t*)(lf_t + ((size_t)b * 1024 + y * 32 + xl) * CCH + ct * 64 + cq) = o;
    } else {
      // ---- convert chunk job: roi_fc_W f32 (k = c*49+p) -> Wb2[kb][h][64]
      int j2 = j - 4096;
      int h  = j2 >> 2;
      int c0 = (j2 & 3) * 128;    // channel chunk base
      const float4* s4 = (const float4*)(roiW + (size_t)h * INDIM + (size_t)c0 * 49);
      for (int i = t; i < 1568; i += 256) {   // 128*49/4 float4
        float4 v = s4[i];
        int k = i * 4;                         // local flat = cc*49 + p
#pragma unroll
        for (int q = 0; q < 4; ++q) {
          int kk = k + q;
          int cc = kk / 49;                    // const divide -> magic mul
          int p  = kk - cc * 49;
          sm.cv[p * 132 + cc] = f2bf((&v.x)[q]);
        }
      }
      __syncthreads();
      // 784 ushort8 outputs: q -> p = q>>4, cc0 = (q&15)*8
      for (int q = t; q < 784; q += 256) {
        int p = q >> 4;
        int cc0 = (q & 15) * 8;
        const u16* sp = &sm.cv[p * 132 + cc0];
        ushort8_t o;
#pragma unroll
        for (int i = 0; i < 8; ++i) o[i] = sp[i];
        int c   = c0 + cc0;
        int kb  = p * 8 + (c >> 6);
        int col = c & 63;
        *(ushort8_t*)(Wb2 + ((size_t)kb * HIDN + h) * 64 + col) = o;
      }
    }
    __syncthreads();   // LDS reuse guard before next job
  }
}

// ---------------- kernel 2: ROI align -> flat2[kb][row][64] bf16 -----------
// Baseline-verified: 416 blocks x 512 threads, XCD-locality swizzle.
__global__ __launch_bounds__(512) void k_roi(const u16* __restrict__ lf_t,
                                             const float* __restrict__ pred,
                                             u16* __restrict__ flat2) {
  __shared__ int   s_ylo[14], s_yhi[14], s_xlo[14], s_xhi[14];
  __shared__ float s_wyl[14], s_wyh[14], s_wxl[14], s_wxh[14];

  int bid = blockIdx.x;          // 0..415
  int xcd = bid & 7;
  int s = bid >> 3;              // 0..51
  int b = xcd * 2 + (s >= 26 ? 1 : 0);
  int n = (s >= 26) ? s - 26 : s;      // always < 26
  int blk = b * 26 + n;          // output row in M=416 space
  int t = threadIdx.x;

  if (t < 28) {
    bool isY = t < 14;
    int j = isY ? t : t - 14;
    const float* p = pred + ((size_t)(b * SS + n)) * 4;
    float c0 = p[0], c1 = p[1], c2 = p[2], c3 = p[3];
    float lo1 = (isY ? c1 : c0) * 32.f;
    float hi1 = (isY ? c3 : c2) * 32.f;
    float sz = fmaxf(hi1 - lo1, 1.f);
    float bs = sz * (1.f / 7.f);
    float off = (float)(j >> 1) + 0.25f + 0.5f * (float)(j & 1);
    float pos = lo1 + off * bs;
    bool valid = (pos > -1.f) && (pos < 32.f);
    float tc = fminf(fmaxf(pos, 0.f), 31.f);
    int lo = (int)floorf(tc);
    int hi = min(lo + 1, 31);
    float fr = tc - (float)lo;
    float wl = valid ? (1.f - fr) : 0.f;
    float wh = valid ? fr : 0.f;
    if (isY) { s_ylo[j] = lo; s_yhi[j] = hi; s_wyl[j] = wl; s_wyh[j] = wh; }
    else     { s_xlo[j] = lo; s_xhi[j] = hi; s_wxl[j] = wl; s_wxh[j] = wh; }
  }
  __syncthreads();

  int cg = t & 63;          // channel group: channels cg*8 .. cg*8+7
  int pg = t >> 6;          // pixel stripe: pixels pg, pg+8, ...
  const u16* base = lf_t + (size_t)b * 1024 * CCH + cg * 8;

  for (int p = pg; p < 49; p += 8) {
    int py = p / 7, px = p % 7;
    v2f a0 = {0.f, 0.f}, a1 = {0.f, 0.f}, a2 = {0.f, 0.f}, a3 = {0.f, 0.f};
#pragma unroll
    for (int sy = 0; sy < 2; ++sy) {
      int jy = 2 * py + sy;
      const u16* rlo = base + s_ylo[jy] * 32 * CCH;
      const u16* rhi = base + s_yhi[jy] * 32 * CCH;
      float wyl = s_wyl[jy], wyh = s_wyh[jy];
#pragma unroll
      for (int sx = 0; sx < 2; ++sx) {
        int jx = 2 * px + sx;
        int xl = s_xlo[jx] * CCH, xh = s_xhi[jx] * CCH;
        v2f wll = {wyl * s_wxl[jx], wyl * s_wxl[jx]};
        v2f wlh = {wyl * s_wxh[jx], wyl * s_wxh[jx]};
        v2f whl = {wyh * s_wxl[jx], wyh * s_wxl[jx]};
        v2f whh = {wyh * s_wxh[jx], wyh * s_wxh[jx]};
        ushort8_t vll = *(const ushort8_t*)(rlo + xl);
        ushort8_t vlh = *(const ushort8_t*)(rlo + xh);
        ushort8_t vhl = *(const ushort8_t*)(rhi + xl);
        ushort8_t vhh = *(const ushort8_t*)(rhi + xh);
        a0 += wll * bf2x2(vll[0], vll[1]) + wlh * bf2x2(vlh[0], vlh[1])
            + whl * bf2x2(vhl[0], vhl[1]) + whh * bf2x2(vhh[0], vhh[1]);
        a1 += wll * bf2x2(vll[2], vll[3]) + wlh * bf2x2(vlh[2], vlh[3])
            + whl * bf2x2(vhl[2], vhl[3]) + whh * bf2x2(vhh[2], vhh[3]);
        a2 += wll * bf2x2(vll[4], vll[5]) + wlh * bf2x2(vlh[4], vlh[5])
            + whl * bf2x2(vhl[4], vhl[5]) + whh * bf2x2(vhh[4], vhh[5]);
        a3 += wll * bf2x2(vll[6], vll[7]) + wlh * bf2x2(vlh[6], vlh[7])
            + whl * bf2x2(vhl[6], vhl[7]) + whh * bf2x2(vhh[6], vhh[7]);
      }
    }
    ushort8_t o;
    o[0] = f2bf(a0.x * 0.25f); o[1] = f2bf(a0.y * 0.25f);
    o[2] = f2bf(a1.x * 0.25f); o[3] = f2bf(a1.y * 0.25f);
    o[4] = f2bf(a2.x * 0.25f); o[5] = f2bf(a2.y * 0.25f);
    o[6] = f2bf(a3.x * 0.25f); o[7] = f2bf(a3.y * 0.25f);
    int kb = p * 8 + (cg >> 3);
    int col = (cg & 7) * 8;
    *(ushort8_t*)(flat2 + ((size_t)kb * M_ROWS + blk) * 64 + col) = o;
  }
}

// ---------------- kernel 3: GEMM, split-K, bf16 MFMA (baseline-verified) ---
__global__ __launch_bounds__(256) void k_gemm(const u16* __restrict__ flat2,
                                              const u16* __restrict__ Wb2,
                                              u16* __restrict__ partials) {
  __shared__ u16 As[128 * 64];   // 16 KB
  __shared__ u16 Bs[128 * 64];   // 16 KB

  int tid = threadIdx.x;
  int wave = tid >> 6, lane = tid & 63;
  int wm = wave >> 1, wn = wave & 1;
  int quad = lane >> 4, r = lane & 15;
  int xb = r & 7;                       // read-side XOR key

  // XCD-owner decode: 896 blocks = 8 XCDs x 7 z x 16 (4 M-tiles x 4 N-tiles)
  int bid = blockIdx.x;
  int xcd = bid & 7;
  int slot = bid >> 3;                  // 0..111
  int z = xcd * 7 + (slot >> 4);        // 0..55
  int xy = slot & 15;
  int tileN0 = (xy & 3) * 128;
  int tileM0 = (xy >> 2) * 128;
  int kb0 = z * KITERS;

  size_t aoff[4], boff[4];
  int    ldso[4];
#pragma unroll
  for (int t = 0; t < 4; ++t) {
    int chunk = (wave * 4 + t) * 64 + lane;
    int row = chunk >> 3;
    int lc = chunk & 7;
    ldso[t] = row * 64 + ((lc ^ (row & 7)) << 3);
    int grow = min(tileM0 + row, M_ROWS - 1);     // clamp M tail
    aoff[t] = ((size_t)kb0 * M_ROWS + grow) * 64 + lc * 8;
    boff[t] = ((size_t)kb0 * HIDN + tileN0 + row) * 64 + lc * 8;
  }

  f32x4 acc[4][4];
#pragma unroll
  for (int mi = 0; mi < 4; ++mi)
#pragma unroll
    for (int ni = 0; ni < 4; ++ni) acc[mi][ni] = (f32x4){0.f, 0.f, 0.f, 0.f};

  short8 ra[4], rb[4];
#pragma unroll
  for (int t = 0; t < 4; ++t) {
    ra[t] = *(const short8*)(flat2 + aoff[t]);
    rb[t] = *(const short8*)(Wb2 + boff[t]);
  }

  for (int kt = 0; kt < KITERS; ++kt) {
#pragma unroll
    for (int t = 0; t < 4; ++t) {
      *(short8*)&As[ldso[t]] = ra[t];
      *(short8*)&Bs[ldso[t]] = rb[t];
    }
    __syncthreads();

    if (kt + 1 < KITERS) {
      size_t ak = (size_t)(kt + 1) * (M_ROWS * 64);
      size_t bk = (size_t)(kt + 1) * (HIDN * 64);
#pragma unroll
      for (int t = 0; t < 4; ++t) {
        ra[t] = *(const short8*)(flat2 + aoff[t] + ak);
        rb[t] = *(const short8*)(Wb2 + boff[t] + bk);
      }
    }

#pragma unroll
    for (int kk = 0; kk < 64; kk += 32) {
      int k8 = kk >> 3;                 // 0 or 4
      int pc = ((k8 + quad) ^ xb) << 3; // physical column (u16 units)
      short8 af[4], bfr[4];
#pragma unroll
      for (int mi = 0; mi < 4; ++mi)
        af[mi] = *(const short8*)&As[(wm * 64 + mi * 16 + r) * 64 + pc];
#pragma unroll
      for (int ni = 0; ni < 4; ++ni)
        bfr[ni] = *(const short8*)&Bs[(wn * 64 + ni * 16 + r) * 64 + pc];
#pragma unroll
      for (int mi = 0; mi < 4; ++mi)
#pragma unroll
        for (int ni = 0; ni < 4; ++ni)
          acc[mi][ni] = __builtin_amdgcn_mfma_f32_16x16x32_bf16(
              af[mi], bfr[ni], acc[mi][ni], 0, 0, 0);
    }
    __syncthreads();
  }

  u16* part = partials + (size_t)z * (M_ROWS * HIDN);
#pragma unroll
  for (int mi = 0; mi < 4; ++mi)
#pragma unroll
    for (int ni = 0; ni < 4; ++ni) {
      int row0 = tileM0 + wm * 64 + mi * 16 + quad * 4;
      int col = tileN0 + wn * 64 + ni * 16 + r;
#pragma unroll
      for (int reg = 0; reg < 4; ++reg) {
        int row = row0 + reg;
        if (row < M_ROWS) part[(size_t)row * HIDN + col] = f2bf(acc[mi][ni][reg]);
      }
    }
}

// ---------------- kernel 4: reduce split-K + bias + relu -> feats ----------
// 2-way z-split per output (28-deep chains, 208 blocks) + shfl_xor combine.
__global__ __launch_bounds__(256) void k_reduce(const u16* __restrict__ partials,
                                                const float* __restrict__ bias,
                                                float* __restrict__ feats) {
  int gid = blockIdx.x * 256 + threadIdx.x;   // < 53248
  int zh  = gid & 1;                          // z-half
  int idx = gid >> 1;                         // 0..26623
  int row = idx >> 6;
  int c0  = (idx & 63) * 8;
  float s[8] = {0.f, 0.f, 0.f, 0.f, 0.f, 0.f, 0.f, 0.f};
  const u16* p = partials + (size_t)row * HIDN + c0
               + (size_t)(zh * 28) * (M_ROWS * HIDN);
  for (int z = 0; z < 28; ++z) {
    ushort8_t v = *(const ushort8_t*)(p + (size_t)z * (M_ROWS * HIDN));
#pragma unroll
    for (int j = 0; j < 8; ++j) s[j] += bf2f(v[j]);
  }
#pragma unroll
  for (int j = 0; j < 8; ++j) s[j] += __shfl_xor(s[j], 1);
  if (zh == 0) {
    float4 o0, o1;
    const float* bi = bias + c0;
    o0.x = fmaxf(s[0] + bi[0], 0.f); o0.y = fmaxf(s[1] + bi[1], 0.f);
    o0.z = fmaxf(s[2] + bi[2], 0.f); o0.w = fmaxf(s[3] + bi[3], 0.f);
    o1.x = fmaxf(s[4] + bi[4], 0.f); o1.y = fmaxf(s[5] + bi[5], 0.f);
    o1.z = fmaxf(s[6] + bi[6], 0.f); o1.w = fmaxf(s[7] + bi[7], 0.f);
    float* dst = feats + (size_t)row * HIDN + c0;
    *(float4*)dst = o0;
    *(float4*)(dst + 4) = o1;
  }
}

// ---------------- kernel 5: all heads, 2 jobs per block (580 blocks) -------
__device__ __forceinline__ float wave_red(float s) {
#pragma unroll
  for (int off = 32; off > 0; off >>= 1) s += __shfl_down(s, off);
  return s;
}

__device__ __forceinline__ float dot512(const float* __restrict__ f,
                                        const float* __restrict__ w, int lane) {
  const float4* f4 = (const float4*)f;
  const float4* w4 = (const float4*)w;
  float4 x0 = f4[lane], y0 = w4[lane];
  float4 x1 = f4[lane + 64], y1 = w4[lane + 64];
  return x0.x * y0.x + x0.y * y0.y + x0.z * y0.z + x0.w * y0.w +
         x1.x * y1.x + x1.y * y1.y + x1.z * y1.z + x1.w * y1.w;
}

__global__ __launch_bounds__(256) void k_heads(const float* __restrict__ feats,
                                               const float* __restrict__ pred,
                                               const float* __restrict__ cW,
                                               const float* __restrict__ cb,
                                               const float* __restrict__ pW,
                                               const float* __restrict__ pb,
                                               const float* __restrict__ lW,
                                               const float* __restrict__ lb,
                                               const float* __restrict__ gW,
                                               const float* __restrict__ gb,
                                               const int* __restrict__ lidx,
                                               const int* __restrict__ gidx,
                                               float* __restrict__ out) {
  int lane = threadIdx.x & 63;

#pragma unroll 1
  for (int h = 0; h < 2; ++h) {
    int wid = (blockIdx.x * 2 + h) * 4 + (threadIdx.x >> 6);   // 0..4639
    float sum = 0.f;

    if (wid < 1664) {                 // refined (B,26,4)
      int b = wid / 104, rr = wid % 104, s = rr >> 2, o = rr & 3;
      sum = dot512(feats + (size_t)(b * 26 + s) * HIDN,
                   cW + (size_t)(s * 4 + o) * HIDN, lane);
      sum = wave_red(sum);
      if (lane == 0) {
        const float* p = pred + (size_t)(b * SS + s) * 4;
        float wdt = p[2] - p[0], hgt = p[3] - p[1];
        float whv = (o & 1) ? hgt : wdt;
        out[wid] = p[o] + (sum + cb[s * 4 + o]) * whv;
      }
    } else if (wid < 2080) {          // presence (B,26)
      int i = wid - 1664;
      int b = i / 26, s = i % 26;
      sum = dot512(feats + (size_t)(b * 26 + s) * HIDN,
                   pW + (size_t)s * HIDN, lane);
      sum = wave_red(sum);
      if (lane == 0) out[1664 + i] = sum + pb[s];
    } else if (wid < 3616) {          // loc (B,12,8)
      int i = wid - 2080;
      int b = i / 96, rr = i % 96, l = rr >> 3, o = rr & 7;
      sum = dot512(feats + (size_t)(b * 26 + lidx[l]) * HIDN,
                   lW + (size_t)(l * 8 + o) * HIDN, lane);
      sum = wave_red(sum);
      if (lane == 0) out[2080 + b * 160 + rr] = sum + lb[l * 8 + o];
    } else {                          // grp (B,4,16), K = 6*512
      int i = wid - 3616;
      int b = i / 64, rr = i % 64, g = rr >> 4, o = rr & 15;
      const float* w = gW + (size_t)(g * 16 + o) * 3072;
#pragma unroll
      for (int jj = 0; jj < 6; ++jj) {
        sum += dot512(feats + (size_t)(b * 26 + gidx[g * 6 + jj]) * HIDN,
                      w + jj * 512, lane);
      }
      sum = wave_red(sum);
      if (lane == 0) out[2080 + b * 160 + 96 + rr] = sum + gb[g * 16 + o];
    }
  }
}

// ---------------------------------------------------------------------------
extern "C" void kernel_launch(void* const* d_in, const int* in_sizes, int n_in,
                              void* d_out, int out_size, void* d_ws, size_t ws_size,
                              hipStream_t stream) {
  const float* lf      = (const float*)d_in[0];
  const float* pred    = (const float*)d_in[1];
  const float* roiW    = (const float*)d_in[2];
  const float* roiB    = (const float*)d_in[3];
  const float* cW      = (const float*)d_in[4];
  const float* cb      = (const float*)d_in[5];
  const float* pW      = (const float*)d_in[6];
  const float* pb      = (const float*)d_in[7];
  const float* lW      = (const float*)d_in[8];
  const float* lb      = (const float*)d_in[9];
  const float* gW      = (const float*)d_in[10];
  const float* gb      = (const float*)d_in[11];
  const int*   lidx    = (const int*)d_in[12];
  const int*   gidx    = (const int*)d_in[13];
  float* out = (float*)d_out;

  char* ws = (char*)d_ws;
  // region 0: lf_t (16.8 MB) then reused by partials bf16 (23.9 MB = 56*416*512*2)
  u16*   lf_t     = (u16*)ws;
  u16*   partials = (u16*)ws;
  u16*   Wb2   = (u16*)(ws + 33030144);                 // 25,690,112 B
  u16*   flat2 = (u16*)(ws + 33030144 + 25690112);      // 20,873,216 B used
  float* feats = (float*)(ws + 33030144 + 25690112 + 28901376); // 851,968 B used

  k_prep<<<1536, 256, 0, stream>>>(lf, roiW, lf_t, Wb2);
  k_roi<<<M_ROWS, 512, 0, stream>>>(lf_t, pred, flat2);
  // NOTE: partials aliases lf_t's region; k_roi (last reader of lf_t) is
  // stream-ordered before k_gemm (first writer of partials).
  k_gemm<<<896, 256, 0, stream>>>(flat2, Wb2, partials);
  k_reduce<<<208, 256, 0, stream>>>(partials, roiB, feats);
  k_heads<<<580, 256, 0, stream>>>(feats, pred, cW, cb, pW, pb, lW, lb, gW, gb,
                                   lidx, gidx, out);
}

// Round 9
// 192.123 us; speedup vs baseline: 1.9661x; 1.0644x over previous
//
#include <hip/hip_runtime.h>

typedef unsigned short u16;
typedef __attribute__((ext_vector_type(8))) short short8;
typedef __attribute__((ext_vector_type(8))) unsigned short ushort8_t;
typedef __attribute__((ext_vector_type(4))) float f32x4;
typedef __attribute__((ext_vector_type(2))) float v2f;

#define BATCH   16
#define CCH     512
#define NBOX    36
#define SS      26
#define INDIM   25088   // 512*49
#define HIDN    512
#define M_ROWS  416     // BATCH*26 — boxes n>=26 never reach an output
#define KSPLIT  56
#define KITERS  7       // per split, BK=64 -> 56*7*64 = 25088
#define NKB     392

__device__ __forceinline__ u16 f2bf(float f) {
  unsigned u = __float_as_uint(f);
  u += 0x7FFF + ((u >> 16) & 1);   // RNE
  return (u16)(u >> 16);
}
__device__ __forceinline__ float bf2f(u16 h) {
  return __uint_as_float(((unsigned)h) << 16);
}
__device__ __forceinline__ v2f bf2x2(u16 a, u16 b) {
  v2f r;
  r.x = __uint_as_float(((unsigned)a) << 16);
  r.y = __uint_as_float(((unsigned)b) << 16);
  return r;
}

// ---------------- kernel 1: transpose lf jobs (0..4095) || convert W jobs
// (4096..6143), one launch, ONE job per block (r8 measured: 4-job coarsening
// serializes latency chains and costs +12us; tiny-block dispatch is cheaper).
__global__ __launch_bounds__(256) void k_prep(const float* __restrict__ lf,
                                              const float* __restrict__ roiW,
                                              u16* __restrict__ lf_t,
                                              u16* __restrict__ Wb2) {
  __shared__ union {
    u16 tr[32][66];       // transpose: 4224 B
    u16 cv[49 * 132];     // convert chunk: 12936 B
  } sm;
  int j = blockIdx.x;
  int t = threadIdx.x;

  if (j < 4096) {
    // ---- transpose job: (B,C,H,W) f32 -> (B,HW,C) bf16
    int ct = j & 7, y = (j >> 3) & 31, b = j >> 8;
    int cl = t >> 2;            // 0..63 channel within tile
    int xq = (t & 3) * 8;       // 8 consecutive x
    const float* src = lf + ((size_t)(b * CCH + ct * 64 + cl) * 1024) + y * 32 + xq;
    float4 v0 = *(const float4*)src;
    float4 v1 = *(const float4*)(src + 4);
    sm.tr[xq + 0][cl] = f2bf(v0.x); sm.tr[xq + 1][cl] = f2bf(v0.y);
    sm.tr[xq + 2][cl] = f2bf(v0.z); sm.tr[xq + 3][cl] = f2bf(v0.w);
    sm.tr[xq + 4][cl] = f2bf(v1.x); sm.tr[xq + 5][cl] = f2bf(v1.y);
    sm.tr[xq + 6][cl] = f2bf(v1.z); sm.tr[xq + 7][cl] = f2bf(v1.w);
    __syncthreads();
    int xl = t >> 3;            // 0..31
    int cq = (t & 7) * 8;       // 8 consecutive channels
    ushort8_t o;
#pragma unroll
    for (int i = 0; i < 8; ++i) o[i] = sm.tr[xl][cq + i];
    *(ushort8_t*)(lf_t + ((size_t)b * 1024 + y * 32 + xl) * CCH + ct * 64 + cq) = o;
  } else {
    // ---- convert chunk job: roi_fc_W f32 (k = c*49+p) -> Wb2[kb][h][64]
    int j2 = j - 4096;
    int h  = j2 >> 2;
    int c0 = (j2 & 3) * 128;    // channel chunk base
    const float4* s4 = (const float4*)(roiW + (size_t)h * INDIM + (size_t)c0 * 49);
    for (int i = t; i < 1568; i += 256) {   // 128*49/4 float4
      float4 v = s4[i];
      int k = i * 4;                         // local flat = cc*49 + p
#pragma unroll
      for (int jj = 0; jj < 4; ++jj) {
        int kk = k + jj;
        int cc = kk / 49;                    // const divide -> magic mul
        int p  = kk - cc * 49;
        sm.cv[p * 132 + cc] = f2bf((&v.x)[jj]);
      }
    }
    __syncthreads();
    // 784 ushort8 outputs: q -> p = q>>4, cc0 = (q&15)*8
    for (int q = t; q < 784; q += 256) {
      int p = q >> 4;
      int cc0 = (q & 15) * 8;
      const u16* sp = &sm.cv[p * 132 + cc0];
      ushort8_t o;
#pragma unroll
      for (int i = 0; i < 8; ++i) o[i] = sp[i];
      int c   = c0 + cc0;
      int kb  = p * 8 + (c >> 6);
      int col = c & 63;
      *(ushort8_t*)(Wb2 + ((size_t)kb * HIDN + h) * 64 + col) = o;
    }
  }
}

// ---------------- kernel 2: ROI align -> flat2[kb][row][64] bf16 -----------
// Baseline-verified: 416 blocks x 512 threads, XCD-locality swizzle.
__global__ __launch_bounds__(512) void k_roi(const u16* __restrict__ lf_t,
                                             const float* __restrict__ pred,
                                             u16* __restrict__ flat2) {
  __shared__ int   s_ylo[14], s_yhi[14], s_xlo[14], s_xhi[14];
  __shared__ float s_wyl[14], s_wyh[14], s_wxl[14], s_wxh[14];

  int bid = blockIdx.x;          // 0..415
  int xcd = bid & 7;
  int s = bid >> 3;              // 0..51
  int b = xcd * 2 + (s >= 26 ? 1 : 0);
  int n = (s >= 26) ? s - 26 : s;      // always < 26
  int blk = b * 26 + n;          // output row in M=416 space
  int t = threadIdx.x;

  if (t < 28) {
    bool isY = t < 14;
    int j = isY ? t : t - 14;
    const float* p = pred + ((size_t)(b * SS + n)) * 4;
    float c0 = p[0], c1 = p[1], c2 = p[2], c3 = p[3];
    float lo1 = (isY ? c1 : c0) * 32.f;
    float hi1 = (isY ? c3 : c2) * 32.f;
    float sz = fmaxf(hi1 - lo1, 1.f);
    float bs = sz * (1.f / 7.f);
    float off = (float)(j >> 1) + 0.25f + 0.5f * (float)(j & 1);
    float pos = lo1 + off * bs;
    bool valid = (pos > -1.f) && (pos < 32.f);
    float tc = fminf(fmaxf(pos, 0.f), 31.f);
    int lo = (int)floorf(tc);
    int hi = min(lo + 1, 31);
    float fr = tc - (float)lo;
    float wl = valid ? (1.f - fr) : 0.f;
    float wh = valid ? fr : 0.f;
    if (isY) { s_ylo[j] = lo; s_yhi[j] = hi; s_wyl[j] = wl; s_wyh[j] = wh; }
    else     { s_xlo[j] = lo; s_xhi[j] = hi; s_wxl[j] = wl; s_wxh[j] = wh; }
  }
  __syncthreads();

  int cg = t & 63;          // channel group: channels cg*8 .. cg*8+7
  int pg = t >> 6;          // pixel stripe: pixels pg, pg+8, ...
  const u16* base = lf_t + (size_t)b * 1024 * CCH + cg * 8;

  for (int p = pg; p < 49; p += 8) {
    int py = p / 7, px = p % 7;
    v2f a0 = {0.f, 0.f}, a1 = {0.f, 0.f}, a2 = {0.f, 0.f}, a3 = {0.f, 0.f};
#pragma unroll
    for (int sy = 0; sy < 2; ++sy) {
      int jy = 2 * py + sy;
      const u16* rlo = base + s_ylo[jy] * 32 * CCH;
      const u16* rhi = base + s_yhi[jy] * 32 * CCH;
      float wyl = s_wyl[jy], wyh = s_wyh[jy];
#pragma unroll
      for (int sx = 0; sx < 2; ++sx) {
        int jx = 2 * px + sx;
        int xl = s_xlo[jx] * CCH, xh = s_xhi[jx] * CCH;
        v2f wll = {wyl * s_wxl[jx], wyl * s_wxl[jx]};
        v2f wlh = {wyl * s_wxh[jx], wyl * s_wxh[jx]};
        v2f whl = {wyh * s_wxl[jx], wyh * s_wxl[jx]};
        v2f whh = {wyh * s_wxh[jx], wyh * s_wxh[jx]};
        ushort8_t vll = *(const ushort8_t*)(rlo + xl);
        ushort8_t vlh = *(const ushort8_t*)(rlo + xh);
        ushort8_t vhl = *(const ushort8_t*)(rhi + xl);
        ushort8_t vhh = *(const ushort8_t*)(rhi + xh);
        a0 += wll * bf2x2(vll[0], vll[1]) + wlh * bf2x2(vlh[0], vlh[1])
            + whl * bf2x2(vhl[0], vhl[1]) + whh * bf2x2(vhh[0], vhh[1]);
        a1 += wll * bf2x2(vll[2], vll[3]) + wlh * bf2x2(vlh[2], vlh[3])
            + whl * bf2x2(vhl[2], vhl[3]) + whh * bf2x2(vhh[2], vhh[3]);
        a2 += wll * bf2x2(vll[4], vll[5]) + wlh * bf2x2(vlh[4], vlh[5])
            + whl * bf2x2(vhl[4], vhl[5]) + whh * bf2x2(vhh[4], vhh[5]);
        a3 += wll * bf2x2(vll[6], vll[7]) + wlh * bf2x2(vlh[6], vlh[7])
            + whl * bf2x2(vhl[6], vhl[7]) + whh * bf2x2(vhh[6], vhh[7]);
      }
    }
    ushort8_t o;
    o[0] = f2bf(a0.x * 0.25f); o[1] = f2bf(a0.y * 0.25f);
    o[2] = f2bf(a1.x * 0.25f); o[3] = f2bf(a1.y * 0.25f);
    o[4] = f2bf(a2.x * 0.25f); o[5] = f2bf(a2.y * 0.25f);
    o[6] = f2bf(a3.x * 0.25f); o[7] = f2bf(a3.y * 0.25f);
    int kb = p * 8 + (cg >> 3);
    int col = (cg & 7) * 8;
    *(ushort8_t*)(flat2 + ((size_t)kb * M_ROWS + blk) * 64 + col) = o;
  }
}

// ---------------- kernel 3: GEMM, split-K, bf16 MFMA (baseline-verified) ---
__global__ __launch_bounds__(256) void k_gemm(const u16* __restrict__ flat2,
                                              const u16* __restrict__ Wb2,
                                              u16* __restrict__ partials) {
  __shared__ u16 As[128 * 64];   // 16 KB
  __shared__ u16 Bs[128 * 64];   // 16 KB

  int tid = threadIdx.x;
  int wave = tid >> 6, lane = tid & 63;
  int wm = wave >> 1, wn = wave & 1;
  int quad = lane >> 4, r = lane & 15;
  int xb = r & 7;                       // read-side XOR key

  // XCD-owner decode: 896 blocks = 8 XCDs x 7 z x 16 (4 M-tiles x 4 N-tiles)
  int bid = blockIdx.x;
  int xcd = bid & 7;
  int slot = bid >> 3;                  // 0..111
  int z = xcd * 7 + (slot >> 4);        // 0..55
  int xy = slot & 15;
  int tileN0 = (xy & 3) * 128;
  int tileM0 = (xy >> 2) * 128;
  int kb0 = z * KITERS;

  size_t aoff[4], boff[4];
  int    ldso[4];
#pragma unroll
  for (int t = 0; t < 4; ++t) {
    int chunk = (wave * 4 + t) * 64 + lane;
    int row = chunk >> 3;
    int lc = chunk & 7;
    ldso[t] = row * 64 + ((lc ^ (row & 7)) << 3);
    int grow = min(tileM0 + row, M_ROWS - 1);     // clamp M tail
    aoff[t] = ((size_t)kb0 * M_ROWS + grow) * 64 + lc * 8;
    boff[t] = ((size_t)kb0 * HIDN + tileN0 + row) * 64 + lc * 8;
  }

  f32x4 acc[4][4];
#pragma unroll
  for (int mi = 0; mi < 4; ++mi)
#pragma unroll
    for (int ni = 0; ni < 4; ++ni) acc[mi][ni] = (f32x4){0.f, 0.f, 0.f, 0.f};

  short8 ra[4], rb[4];
#pragma unroll
  for (int t = 0; t < 4; ++t) {
    ra[t] = *(const short8*)(flat2 + aoff[t]);
    rb[t] = *(const short8*)(Wb2 + boff[t]);
  }

  for (int kt = 0; kt < KITERS; ++kt) {
#pragma unroll
    for (int t = 0; t < 4; ++t) {
      *(short8*)&As[ldso[t]] = ra[t];
      *(short8*)&Bs[ldso[t]] = rb[t];
    }
    __syncthreads();

    if (kt + 1 < KITERS) {
      size_t ak = (size_t)(kt + 1) * (M_ROWS * 64);
      size_t bk = (size_t)(kt + 1) * (HIDN * 64);
#pragma unroll
      for (int t = 0; t < 4; ++t) {
        ra[t] = *(const short8*)(flat2 + aoff[t] + ak);
        rb[t] = *(const short8*)(Wb2 + boff[t] + bk);
      }
    }

#pragma unroll
    for (int kk = 0; kk < 64; kk += 32) {
      int k8 = kk >> 3;                 // 0 or 4
      int pc = ((k8 + quad) ^ xb) << 3; // physical column (u16 units)
      short8 af[4], bfr[4];
#pragma unroll
      for (int mi = 0; mi < 4; ++mi)
        af[mi] = *(const short8*)&As[(wm * 64 + mi * 16 + r) * 64 + pc];
#pragma unroll
      for (int ni = 0; ni < 4; ++ni)
        bfr[ni] = *(const short8*)&Bs[(wn * 64 + ni * 16 + r) * 64 + pc];
#pragma unroll
      for (int mi = 0; mi < 4; ++mi)
#pragma unroll
        for (int ni = 0; ni < 4; ++ni)
          acc[mi][ni] = __builtin_amdgcn_mfma_f32_16x16x32_bf16(
              af[mi], bfr[ni], acc[mi][ni], 0, 0, 0);
    }
    __syncthreads();
  }

  u16* part = partials + (size_t)z * (M_ROWS * HIDN);
#pragma unroll
  for (int mi = 0; mi < 4; ++mi)
#pragma unroll
    for (int ni = 0; ni < 4; ++ni) {
      int row0 = tileM0 + wm * 64 + mi * 16 + quad * 4;
      int col = tileN0 + wn * 64 + ni * 16 + r;
#pragma unroll
      for (int reg = 0; reg < 4; ++reg) {
        int row = row0 + reg;
        if (row < M_ROWS) part[(size_t)row * HIDN + col] = f2bf(acc[mi][ni][reg]);
      }
    }
}

// ---------------- kernel 4: reduce split-K + bias + relu -> feats ----------
// 2-way z-split per output (28-deep chains, 208 blocks) + shfl_xor combine.
__global__ __launch_bounds__(256) void k_reduce(const u16* __restrict__ partials,
                                                const float* __restrict__ bias,
                                                float* __restrict__ feats) {
  int gid = blockIdx.x * 256 + threadIdx.x;   // < 53248
  int zh  = gid & 1;                          // z-half
  int idx = gid >> 1;                         // 0..26623
  int row = idx >> 6;
  int c0  = (idx & 63) * 8;
  float s[8] = {0.f, 0.f, 0.f, 0.f, 0.f, 0.f, 0.f, 0.f};
  const u16* p = partials + (size_t)row * HIDN + c0
               + (size_t)(zh * 28) * (M_ROWS * HIDN);
  for (int z = 0; z < 28; ++z) {
    ushort8_t v = *(const ushort8_t*)(p + (size_t)z * (M_ROWS * HIDN));
#pragma unroll
    for (int j = 0; j < 8; ++j) s[j] += bf2f(v[j]);
  }
#pragma unroll
  for (int j = 0; j < 8; ++j) s[j] += __shfl_xor(s[j], 1);
  if (zh == 0) {
    float4 o0, o1;
    const float* bi = bias + c0;
    o0.x = fmaxf(s[0] + bi[0], 0.f); o0.y = fmaxf(s[1] + bi[1], 0.f);
    o0.z = fmaxf(s[2] + bi[2], 0.f); o0.w = fmaxf(s[3] + bi[3], 0.f);
    o1.x = fmaxf(s[4] + bi[4], 0.f); o1.y = fmaxf(s[5] + bi[5], 0.f);
    o1.z = fmaxf(s[6] + bi[6], 0.f); o1.w = fmaxf(s[7] + bi[7], 0.f);
    float* dst = feats + (size_t)row * HIDN + c0;
    *(float4*)dst = o0;
    *(float4*)(dst + 4) = o1;
  }
}

// ---------------- kernel 5: all heads, one wave per output dot -------------
__device__ __forceinline__ float wave_red(float s) {
#pragma unroll
  for (int off = 32; off > 0; off >>= 1) s += __shfl_down(s, off);
  return s;
}

__device__ __forceinline__ float dot512(const float* __restrict__ f,
                                        const float* __restrict__ w, int lane) {
  const float4* f4 = (const float4*)f;
  const float4* w4 = (const float4*)w;
  float4 x0 = f4[lane], y0 = w4[lane];
  float4 x1 = f4[lane + 64], y1 = w4[lane + 64];
  return x0.x * y0.x + x0.y * y0.y + x0.z * y0.z + x0.w * y0.w +
         x1.x * y1.x + x1.y * y1.y + x1.z * y1.z + x1.w * y1.w;
}

__global__ __launch_bounds__(256) void k_heads(const float* __restrict__ feats,
                                               const float* __restrict__ pred,
                                               const float* __restrict__ cW,
                                               const float* __restrict__ cb,
                                               const float* __restrict__ pW,
                                               const float* __restrict__ pb,
                                               const float* __restrict__ lW,
                                               const float* __restrict__ lb,
                                               const float* __restrict__ gW,
                                               const float* __restrict__ gb,
                                               const int* __restrict__ lidx,
                                               const int* __restrict__ gidx,
                                               float* __restrict__ out) {
  int wid = blockIdx.x * 4 + (threadIdx.x >> 6);   // 0..4639
  int lane = threadIdx.x & 63;
  float sum = 0.f;

  if (wid < 1664) {                 // refined (B,26,4)
    int b = wid / 104, rr = wid % 104, s = rr >> 2, o = rr & 3;
    sum = dot512(feats + (size_t)(b * 26 + s) * HIDN,
                 cW + (size_t)(s * 4 + o) * HIDN, lane);
    sum = wave_red(sum);
    if (lane == 0) {
      const float* p = pred + (size_t)(b * SS + s) * 4;
      float wdt = p[2] - p[0], hgt = p[3] - p[1];
      float whv = (o & 1) ? hgt : wdt;
      out[wid] = p[o] + (sum + cb[s * 4 + o]) * whv;
    }
  } else if (wid < 2080) {          // presence (B,26)
    int i = wid - 1664;
    int b = i / 26, s = i % 26;
    sum = dot512(feats + (size_t)(b * 26 + s) * HIDN,
                 pW + (size_t)s * HIDN, lane);
    sum = wave_red(sum);
    if (lane == 0) out[1664 + i] = sum + pb[s];
  } else if (wid < 3616) {          // loc (B,12,8)
    int i = wid - 2080;
    int b = i / 96, rr = i % 96, l = rr >> 3, o = rr & 7;
    sum = dot512(feats + (size_t)(b * 26 + lidx[l]) * HIDN,
                 lW + (size_t)(l * 8 + o) * HIDN, lane);
    sum = wave_red(sum);
    if (lane == 0) out[2080 + b * 160 + rr] = sum + lb[l * 8 + o];
  } else {                          // grp (B,4,16), K = 6*512
    int i = wid - 3616;
    int b = i / 64, rr = i % 64, g = rr >> 4, o = rr & 15;
    const float* w = gW + (size_t)(g * 16 + o) * 3072;
#pragma unroll
    for (int jj = 0; jj < 6; ++jj) {
      sum += dot512(feats + (size_t)(b * 26 + gidx[g * 6 + jj]) * HIDN,
                    w + jj * 512, lane);
    }
    sum = wave_red(sum);
    if (lane == 0) out[2080 + b * 160 + 96 + rr] = sum + gb[g * 16 + o];
  }
}

// ---------------------------------------------------------------------------
extern "C" void kernel_launch(void* const* d_in, const int* in_sizes, int n_in,
                              void* d_out, int out_size, void* d_ws, size_t ws_size,
                              hipStream_t stream) {
  const float* lf      = (const float*)d_in[0];
  const float* pred    = (const float*)d_in[1];
  const float* roiW    = (const float*)d_in[2];
  const float* roiB    = (const float*)d_in[3];
  const float* cW      = (const float*)d_in[4];
  const float* cb      = (const float*)d_in[5];
  const float* pW      = (const float*)d_in[6];
  const float* pb      = (const float*)d_in[7];
  const float* lW      = (const float*)d_in[8];
  const float* lb      = (const float*)d_in[9];
  const float* gW      = (const float*)d_in[10];
  const float* gb      = (const float*)d_in[11];
  const int*   lidx    = (const int*)d_in[12];
  const int*   gidx    = (const int*)d_in[13];
  float* out = (float*)d_out;

  char* ws = (char*)d_ws;
  // region 0: lf_t (16.8 MB) then reused by partials bf16 (23.9 MB = 56*416*512*2)
  u16*   lf_t     = (u16*)ws;
  u16*   partials = (u16*)ws;
  u16*   Wb2   = (u16*)(ws + 33030144);                 // 25,690,112 B
  u16*   flat2 = (u16*)(ws + 33030144 + 25690112);      // 20,873,216 B used
  float* feats = (float*)(ws + 33030144 + 25690112 + 28901376); // 851,968 B used

  k_prep<<<6144, 256, 0, stream>>>(lf, roiW, lf_t, Wb2);
  k_roi<<<M_ROWS, 512, 0, stream>>>(lf_t, pred, flat2);
  // NOTE: partials aliases lf_t's region; k_roi (last reader of lf_t) is
  // stream-ordered before k_gemm (first writer of partials).
  k_gemm<<<896, 256, 0, stream>>>(flat2, Wb2, partials);
  k_reduce<<<208, 256, 0, stream>>>(partials, roiB, feats);
  k_heads<<<1160, 256, 0, stream>>>(feats, pred, cW, cb, pW, pb, lW, lb, gW, gb,
                                    lidx, gidx, out);
}